// Round 1
// 329.191 us; speedup vs baseline: 1.0910x; 1.0910x over previous
//
#include <hip/hip_runtime.h>
#include <hip/hip_fp16.h>
#include <math.h>

#define Hh 160
#define Ww 160
#define Cc 128
#define HW 25600
#define NPIX 102400   // N*H*W, N=4

typedef __attribute__((ext_vector_type(8))) _Float16 half8;
typedef __attribute__((ext_vector_type(4))) float f32x4;
typedef __attribute__((ext_vector_type(4))) unsigned int u32x4;

union h2u { __half2 h; unsigned int u; };

// ws byte layout (all 16B aligned)
#define WS_OFFS 0u             // 9*102400*2*4 = 7372800  [k][p][2] fp32
#define WS_WA   7372800u       // 9*128*128*2 = 294912  fp16 [k][o][c]
#define WS_GSUM 7667712u       // 512
#define WS_GSQ  7668224u       // 512
#define WS_XT   7668736u       // 102400*128*2 = 26214400 (fp16 NHWC)
#define WS_RAW  33883136u      // 4*128*25600*4 = 52428800

// --------------------------------------------------------------------------
// Kernel W: w_dcn [o][c][k] -> wA fp16 [k][o][c]
__global__ void wtrans_kernel(const float* __restrict__ w_dcn,
                              unsigned short* __restrict__ wA) {
    int idx = blockIdx.x * 256 + threadIdx.x;
    if (idx >= 9 * 128 * 128) return;
    int k = idx >> 14;
    int o = (idx >> 7) & 127;
    int c = idx & 127;
    wA[idx] = __half_as_ushort(__float2half(w_dcn[(o * 128 + c) * 9 + k]));
}

// --------------------------------------------------------------------------
// Kernel X: NCHW fp32 -> NHWC fp16 transpose via LDS tile
__global__ void __launch_bounds__(256) xpose_kernel(
    const float* __restrict__ x, unsigned short* __restrict__ xT) {
    __shared__ float L[128 * 65];
    int b = blockIdx.x;
    int n = b / 400;
    int px0 = (b - n * 400) * 64;
    int t = threadIdx.x;
    const float* xn = x + (size_t)n * Cc * HW + px0;
#pragma unroll
    for (int i = 0; i < 32; ++i) {
        int idx = i * 256 + t;
        int ch = idx >> 6;
        int pxl = idx & 63;
        L[ch * 65 + pxl] = xn[(size_t)ch * HW + pxl];
    }
    __syncthreads();
    unsigned short* dst = xT + ((size_t)n * HW + px0) * 128;
#pragma unroll
    for (int j = 0; j < 16; ++j) {
        int idx = j * 256 + t;
        int pxl = idx >> 6;
        int cp = idx & 63;
        h2u cv;
        cv.h = __floats2half2_rn(L[(2 * cp) * 65 + pxl],
                                 L[(2 * cp + 1) * 65 + pxl]);
        *(unsigned int*)(dst + (size_t)pxl * 128 + cp * 2) = cv.u;
    }
}

// --------------------------------------------------------------------------
// Kernel A: fused tm/tr 3x3 convs -> offs2[k][p][2] (py,px per tap)
__global__ void __launch_bounds__(256) offs_kernel(
    const float* __restrict__ x, const float* __restrict__ w_tm,
    const float* __restrict__ b_tm, const float* __restrict__ w_tr,
    const float* __restrict__ b_tr, float* __restrict__ offs2) {
    __shared__ float wt[128 * 9 * 8];
    int t = threadIdx.x;
    for (int idx = t; idx < 6912; idx += 256) {
        int j = idx % 6;
        int rest = idx / 6;
        int tap = rest % 9;
        int c = rest / 9;
        float v = (j < 4) ? w_tm[(j * 128 + c) * 9 + tap]
                          : w_tr[((j - 4) * 128 + c) * 9 + tap];
        wt[rest * 8 + j] = v;
    }
    __syncthreads();
    int bid = blockIdx.x;                  // 400 blocks, XCD-contiguous slices
    int blk = (bid & 7) * 50 + (bid >> 3);
    int p = blk * 256 + t;
    int n = p / HW;
    int hw = p - n * HW;
    int h = hw / Ww;
    int w = hw - h * Ww;
    int addr[9];
    float msk[9];
#pragma unroll
    for (int tap = 0; tap < 9; ++tap) {
        int dy = tap / 3 - 1, dx = tap % 3 - 1;
        int yy = h + dy, xx = w + dx;
        bool v = (yy >= 0) && (yy < Hh) && (xx >= 0) && (xx < Ww);
        addr[tap] = v ? yy * Ww + xx : 0;
        msk[tap] = v ? 1.f : 0.f;
    }
    float a0 = 0, a1 = 0, a2 = 0, a3 = 0, a4 = 0, a5 = 0;
    const float* xn = x + n * Cc * HW;
#pragma unroll 2
    for (int c = 0; c < Cc; ++c) {
        const float* xc = xn + c * HW;
#pragma unroll
        for (int tap = 0; tap < 9; ++tap) {
            float v = msk[tap] * xc[addr[tap]];
            const float* wp = &wt[(c * 9 + tap) * 8];
            float4 w4 = *(const float4*)wp;
            float2 w2 = *(const float2*)(wp + 4);
            a0 += v * w4.x; a1 += v * w4.y; a2 += v * w4.z; a3 += v * w4.w;
            a4 += v * w2.x; a5 += v * w2.y;
        }
    }
    a0 += b_tm[0]; a1 += b_tm[1]; a2 += b_tm[2]; a3 += b_tm[3];
    a4 += b_tr[0]; a5 += b_tr[1];
#pragma unroll
    for (int k = 0; k < 9; ++k) {
        float r0 = (float)(k / 3) - 1.f;
        float r1 = (float)(k % 3) - 1.f;
        float2 st;
        st.x = (float)h + a0 * r0 + a1 * r1 + a4;
        st.y = (float)w + a2 * r0 + a3 * r1 + a5;
        *(float2*)(offs2 + ((size_t)k * NPIX + p) * 2) = st;
    }
}

// --------------------------------------------------------------------------
// Kernel D: FUSED deformable conv (fp16). Block = 128px x 128o, XCD-swizzled.
// Staging: 4 px per wave-round, 16 lanes per 256B corner cell -> every gather
// is 4-line coalesced; corners combined in-register with v_pk_fma_f16.
// This rev: latency pipeline for the gather phase —
//   (a) all 8 offs2 loads hoisted ahead of the gather rounds,
//   (b) next tap's offsets prefetched at stage start (hide under gathers),
//   (c) gather rounds fully unrolled,
//   (d) launch_bounds(256,2) so regalloc can keep ~4 rounds in flight.
__global__ void __launch_bounds__(256, 2) dcn2_kernel(
    const unsigned short* __restrict__ xT, const float* __restrict__ offs2,
    const unsigned short* __restrict__ wA, float* __restrict__ raw,
    float* __restrict__ gsum, float* __restrict__ gsq) {
    __shared__ __align__(16) unsigned short Bt[128 * 128];   // 32 KB
    int t = threadIdx.x;
    int lane = t & 63;
    int wid = t >> 6;
    int wm = wid & 1, wn = wid >> 1;
    int quad = lane >> 4, l15 = lane & 15;
    int sub = lane >> 4;                   // staging: px sub-index 0..3
    int s = lane & 15;                     // staging: 16B segment 0..15

    int bid = blockIdx.x;
    int blk = (bid & 7) * 100 + (bid >> 3);   // XCD-contiguous px slices
    int px0 = blk * 128;
    int n = px0 / HW;
    int hw0 = px0 - n * HW;
    const unsigned short* xb = xT + (size_t)n * HW * 128;
    const char* Ag = (const char*)wA;
    const float2* offv = (const float2*)offs2;
    int pbase = px0 + wid * 32 + sub;      // this thread's px stream (stride 4)
    int sb = s << 3;

    f32x4 acc[4][4];
#pragma unroll
    for (int i = 0; i < 4; ++i)
#pragma unroll
        for (int j = 0; j < 4; ++j) acc[i][j] = (f32x4)0.f;

    // preload tap-0 offsets (8 independent 8B loads, all in flight)
    float2 pc[8];
#pragma unroll
    for (int r = 0; r < 8; ++r)
        pc[r] = offv[(size_t)0 * NPIX + pbase + r * 4];

    for (int k = 0; k < 9; ++k) {
        __syncthreads();                   // prev tap's MFMA reads done

        // prefetch NEXT tap's offsets now; latency hides under this tap's
        // gathers (their vmcnt drain at the next barrier is free — the
        // gathers are consumed before it anyway).
        float2 pcn[8];
        if (k < 8) {
#pragma unroll
            for (int r = 0; r < 8; ++r)
                pcn[r] = offv[(size_t)(k + 1) * NPIX + pbase + r * 4];
        }

#pragma unroll
        for (int r = 0; r < 8; ++r) {
            int p = wid * 32 + r * 4 + sub;
            float py = pc[r].x, pxx = pc[r].y;
            float y0f = floorf(py), x0f = floorf(pxx);
            float fy = py - y0f, fx = pxx - x0f;
            int y0 = (int)y0f, xi0 = (int)x0f;
            int y1 = y0 + 1, xi1 = xi0 + 1;
            float w00 = (1.f - fy) * (1.f - fx), w01 = (1.f - fy) * fx;
            float w10 = fy * (1.f - fx), w11 = fy * fx;
            bool vy0 = (unsigned)y0 < (unsigned)Hh;
            bool vy1 = (unsigned)y1 < (unsigned)Hh;
            bool vx0 = (unsigned)xi0 < (unsigned)Ww;
            bool vx1 = (unsigned)xi1 < (unsigned)Ww;
            w00 = (vy0 && vx0) ? w00 : 0.f;
            w01 = (vy0 && vx1) ? w01 : 0.f;
            w10 = (vy1 && vx0) ? w10 : 0.f;
            w11 = (vy1 && vx1) ? w11 : 0.f;
            int cy0 = vy0 ? y0 : 0, cy1 = vy1 ? y1 : 0;
            int cx0 = vx0 ? xi0 : 0, cx1 = vx1 ? xi1 : 0;
            u32x4 v00 = *(const u32x4*)(xb + ((size_t)(cy0 * Ww + cx0) << 7) + sb);
            u32x4 v01 = *(const u32x4*)(xb + ((size_t)(cy0 * Ww + cx1) << 7) + sb);
            u32x4 v10 = *(const u32x4*)(xb + ((size_t)(cy1 * Ww + cx0) << 7) + sb);
            u32x4 v11 = *(const u32x4*)(xb + ((size_t)(cy1 * Ww + cx1) << 7) + sb);
            __half2 W00 = __float2half2_rn(w00);
            __half2 W01 = __float2half2_rn(w01);
            __half2 W10 = __float2half2_rn(w10);
            __half2 W11 = __float2half2_rn(w11);
            u32x4 outv;
#pragma unroll
            for (int e = 0; e < 4; ++e) {
                h2u a, b, c, d, o;
                a.u = v00[e]; b.u = v01[e]; c.u = v10[e]; d.u = v11[e];
                __half2 acc2 = __hmul2(W11, d.h);
                acc2 = __hfma2(W10, c.h, acc2);
                acc2 = __hfma2(W01, b.h, acc2);
                acc2 = __hfma2(W00, a.h, acc2);
                o.h = acc2;
                outv[e] = o.u;
            }
            *(u32x4*)&Bt[p * 128 + ((s ^ (p & 15)) << 3)] = outv;
        }
        __syncthreads();

#pragma unroll
        for (int q = 0; q < 4; ++q) {
            half8 a[4], b[4];
#pragma unroll
            for (int i = 0; i < 4; ++i)
                a[i] = *(const half8*)(Ag +
                        ((size_t)(k * 128 + wm * 64 + i * 16 + l15) << 8) +
                        q * 64 + quad * 16);
#pragma unroll
            for (int j = 0; j < 4; ++j) {
                int row = wn * 64 + j * 16 + l15;
                int ur = (q * 4 + quad) ^ (row & 15);
                b[j] = *(const half8*)&Bt[row * 128 + ur * 8];
            }
#pragma unroll
            for (int i = 0; i < 4; ++i)
#pragma unroll
                for (int j = 0; j < 4; ++j)
                    acc[i][j] = __builtin_amdgcn_mfma_f32_16x16x32_f16(
                        a[i], b[j], acc[i][j], 0, 0, 0);
        }

        if (k < 8) {
#pragma unroll
            for (int r = 0; r < 8; ++r) pc[r] = pcn[r];
        }
    }

    // ---- epilogue: raw out (D[m=o][n=px]) + group sums ----
    size_t rbase = ((size_t)n * Cc) * HW + hw0;
#pragma unroll
    for (int i = 0; i < 4; ++i) {
        float s_i = 0.f, q_i = 0.f;
#pragma unroll
        for (int j = 0; j < 4; ++j) {
            int pxl = wn * 64 + j * 16 + l15;
#pragma unroll
            for (int rr = 0; rr < 4; ++rr) {
                int o = wm * 64 + i * 16 + quad * 4 + rr;
                float v = acc[i][j][rr];
                raw[rbase + (size_t)o * HW + pxl] = v;
                s_i += v;
                q_i += v * v;
            }
        }
#pragma unroll
        for (int m = 1; m < 16; m <<= 1) {
            s_i += __shfl_xor(s_i, m);
            q_i += __shfl_xor(q_i, m);
        }
        if (l15 == 0) {
            int g = wm * 16 + i * 4 + quad;
            atomicAdd(&gsum[n * 32 + g], s_i);
            atomicAdd(&gsq[n * 32 + g], q_i);
        }
    }
}

// --------------------------------------------------------------------------
// Kernel C: GroupNorm finalize + residual + ReLU (float4)
__global__ void __launch_bounds__(256) finish_kernel(
    const float* __restrict__ raw, const float* __restrict__ x,
    const float* __restrict__ gsum, const float* __restrict__ gsq,
    const float* __restrict__ gamma, const float* __restrict__ beta,
    float* __restrict__ out) {
    int i = blockIdx.x * 256 + threadIdx.x;
    int e = i * 4;
    int n = e / (Cc * HW);
    int rem = e - n * (Cc * HW);
    int c = rem / HW;
    int g = c >> 2;
    const float inv = 1.f / 102400.f;
    float mu = gsum[n * 32 + g] * inv;
    float var = gsq[n * 32 + g] * inv - mu * mu;
    float rs = rsqrtf(var + 1e-5f);
    float sc = gamma[c] * rs;
    float sh = beta[c] - mu * sc;
    float4 v = *(const float4*)&raw[e];
    float4 xv = *(const float4*)&x[e];
    float4 r;
    r.x = fmaxf(v.x * sc + sh + xv.x, 0.f);
    r.y = fmaxf(v.y * sc + sh + xv.y, 0.f);
    r.z = fmaxf(v.z * sc + sh + xv.z, 0.f);
    r.w = fmaxf(v.w * sc + sh + xv.w, 0.f);
    *(float4*)&out[e] = r;
}

// --------------------------------------------------------------------------
extern "C" void kernel_launch(void* const* d_in, const int* in_sizes, int n_in,
                              void* d_out, int out_size, void* d_ws, size_t ws_size,
                              hipStream_t stream) {
    const float* x      = (const float*)d_in[0];
    const float* w_tm   = (const float*)d_in[1];
    const float* b_tm   = (const float*)d_in[2];
    const float* w_tr   = (const float*)d_in[3];
    const float* b_tr   = (const float*)d_in[4];
    const float* w_dcn  = (const float*)d_in[5];
    const float* gamma  = (const float*)d_in[6];
    const float* beta   = (const float*)d_in[7];
    char* ws = (char*)d_ws;
    float*          offs2 = (float*)(ws + WS_OFFS);
    unsigned short* wA    = (unsigned short*)(ws + WS_WA);
    float*          gsum  = (float*)(ws + WS_GSUM);
    float*          gsq   = (float*)(ws + WS_GSQ);
    unsigned short* xT    = (unsigned short*)(ws + WS_XT);
    float*          raw   = (float*)(ws + WS_RAW);
    float* out = (float*)d_out;

    (void)hipMemsetAsync(gsum, 0, 1024, stream);   // gsum + gsq
    wtrans_kernel<<<576, 256, 0, stream>>>(w_dcn, wA);
    xpose_kernel<<<1600, 256, 0, stream>>>(x, xT);
    offs_kernel<<<400, 256, 0, stream>>>(x, w_tm, b_tm, w_tr, b_tr, offs2);
    dcn2_kernel<<<800, 256, 0, stream>>>(xT, offs2, wA, raw, gsum, gsq);
    finish_kernel<<<12800, 256, 0, stream>>>(raw, x, gsum, gsq, gamma, beta, out);
}